// Round 1
// baseline (818.013 us; speedup 1.0000x reference)
//
#include <hip/hip_runtime.h>
#include <math.h>

#define NB 2
#define NH 8
#define NS 2048
#define ND 64
#define NBH (NB * NH)
#define QT 8                 // q rows per block
#define KTILE 128            // k rows per staged tile
#define NTILE (NS / KTILE)   // 16
#define NTHREADS 256
#define KSTR 68              // padded LDS row stride in floats (17 x float4)

// LDS layout (floats)
#define SQ_OFF (KTILE * KSTR)          // sK: 128*68 = 8704
#define SP_OFF (SQ_OFF + QT * KSTR)    // sQ: 8*68 = 544   -> 9248
#define SM_OFF (SP_OFF + QT * KTILE)   // sP: 8*128 = 1024 -> 10272
#define SMEM_FLOATS (SM_OFF + NS)      // sM: 2048 ints    -> 12320 floats = 49280 B

__global__ __launch_bounds__(NTHREADS, 3)
void attn_fp32_kernel(const float* __restrict__ Qg, const float* __restrict__ Kg,
                      const float* __restrict__ Vg, const int* __restrict__ Mg,
                      float* __restrict__ outO, float* __restrict__ outP)
{
    __shared__ float smem[SMEM_FLOATS];
    float* sK = smem;                    // [128][68], reused for V tiles and final reduce
    float* sQ = smem + SQ_OFF;           // [8][68]
    float* sP = smem + SP_OFF;           // [8][128]
    int*   sM = (int*)(smem + SM_OFF);   // [2048]

    const int tid = threadIdx.x;
    const int w   = tid >> 6;        // wave 0..3
    const int l   = tid & 63;        // lane
    const int bh  = blockIdx.x >> 8; // 256 q-tiles per (b,h)
    const int qt  = blockIdx.x & 255;
    const int q0  = qt * QT;
    const int bb  = bh >> 3;         // batch index (H = 8)

    const size_t base = (size_t)bh * NS * ND;

    // stage mask (2048 ints) and Q rows (8 x 64 floats)
    for (int i = tid; i < NS; i += NTHREADS) sM[i] = Mg[bb * NS + i];
    if (tid < 128) {
        const int r = tid >> 4, c = tid & 15;
        ((float4*)(sQ + r * KSTR))[c] =
            ((const float4*)(Qg + base + (size_t)(q0 + r) * ND))[c];
    }

    // score ownership: row rr = 2*w + (l>>5) (half-wave per row);
    // lane half-index hh holds k = hh + 32*comp + 128*tile
    const int rr = 2 * w + (l >> 5);
    const int hh = l & 31;

    float4 scr[NTILE];

    // ---------------- QK^T + exp/scale + mask ----------------
    #pragma unroll
    for (int kt = 0; kt < NTILE; ++kt) {
        const float4* gK = (const float4*)(Kg + base + (size_t)kt * KTILE * ND);
        #pragma unroll
        for (int i = 0; i < 8; ++i) {
            const int f = tid + NTHREADS * i;          // 0..2047 float4s
            ((float4*)(sK + (f >> 4) * KSTR))[f & 15] = gK[f];
        }
        __syncthreads();

        float4 a0 = {0.f, 0.f, 0.f, 0.f}, a1 = a0, a2 = a0, a3 = a0;
        const float4* q4  = (const float4*)(sQ + rr * KSTR);
        const float4* k0p = (const float4*)(sK + (hh +  0) * KSTR);
        const float4* k1p = (const float4*)(sK + (hh + 32) * KSTR);
        const float4* k2p = (const float4*)(sK + (hh + 64) * KSTR);
        const float4* k3p = (const float4*)(sK + (hh + 96) * KSTR);
        #pragma unroll 2
        for (int c = 0; c < 16; ++c) {
            const float4 qv = q4[c];
            float4 kv;
            kv = k0p[c];
            a0.x = fmaf(qv.x, kv.x, a0.x); a0.y = fmaf(qv.y, kv.y, a0.y);
            a0.z = fmaf(qv.z, kv.z, a0.z); a0.w = fmaf(qv.w, kv.w, a0.w);
            kv = k1p[c];
            a1.x = fmaf(qv.x, kv.x, a1.x); a1.y = fmaf(qv.y, kv.y, a1.y);
            a1.z = fmaf(qv.z, kv.z, a1.z); a1.w = fmaf(qv.w, kv.w, a1.w);
            kv = k2p[c];
            a2.x = fmaf(qv.x, kv.x, a2.x); a2.y = fmaf(qv.y, kv.y, a2.y);
            a2.z = fmaf(qv.z, kv.z, a2.z); a2.w = fmaf(qv.w, kv.w, a2.w);
            kv = k3p[c];
            a3.x = fmaf(qv.x, kv.x, a3.x); a3.y = fmaf(qv.y, kv.y, a3.y);
            a3.z = fmaf(qv.z, kv.z, a3.z); a3.w = fmaf(qv.w, kv.w, a3.w);
        }
        const float s0 = (a0.x + a0.y) + (a0.z + a0.w);
        const float s1 = (a1.x + a1.y) + (a1.z + a1.w);
        const float s2 = (a2.x + a2.y) + (a2.z + a2.w);
        const float s3 = (a3.x + a3.y) + (a3.z + a3.w);
        const int kg = kt * KTILE + hh;
        float4 sc;
        sc.x = sM[kg     ] ? expf(s0) * 0.125f : -1e9f;
        sc.y = sM[kg + 32] ? expf(s1) * 0.125f : -1e9f;
        sc.z = sM[kg + 64] ? expf(s2) * 0.125f : -1e9f;
        sc.w = sM[kg + 96] ? expf(s3) * 0.125f : -1e9f;
        scr[kt] = sc;
        __syncthreads();
    }

    // ---------------- softmax over registers (half-wave = one row) ----------------
    float m = -3.0e38f;
    #pragma unroll
    for (int j = 0; j < NTILE; ++j)
        m = fmaxf(m, fmaxf(fmaxf(scr[j].x, scr[j].y), fmaxf(scr[j].z, scr[j].w)));
    #pragma unroll
    for (int dd = 1; dd < 32; dd <<= 1) m = fmaxf(m, __shfl_xor(m, dd, 64));

    float ssum = 0.f;
    #pragma unroll
    for (int j = 0; j < NTILE; ++j) {
        float4 e;
        e.x = expf(scr[j].x - m); e.y = expf(scr[j].y - m);
        e.z = expf(scr[j].z - m); e.w = expf(scr[j].w - m);
        scr[j] = e;
        ssum += (e.x + e.y) + (e.z + e.w);
    }
    #pragma unroll
    for (int dd = 1; dd < 32; dd <<= 1) ssum += __shfl_xor(ssum, dd, 64);
    const float inv = 1.0f / ssum;

    // ---------------- write p_attn ----------------
    {
        float* pOut = outP + ((size_t)(bh * NS + q0 + rr)) * NS;
        #pragma unroll
        for (int j = 0; j < NTILE; ++j) {
            pOut[j * KTILE + hh     ] = scr[j].x * inv;
            pOut[j * KTILE + hh + 32] = scr[j].y * inv;
            pOut[j * KTILE + hh + 64] = scr[j].z * inv;
            pOut[j * KTILE + hh + 96] = scr[j].w * inv;
        }
    }

    // ---------------- PV: out = p @ V ----------------
    float po[QT];
    #pragma unroll
    for (int r = 0; r < QT; ++r) po[r] = 0.f;

    #pragma unroll
    for (int kt = 0; kt < NTILE; ++kt) {
        // hand p tile to LDS (register owners -> [8][128])
        sP[rr * KTILE + hh     ] = scr[kt].x * inv;
        sP[rr * KTILE + hh + 32] = scr[kt].y * inv;
        sP[rr * KTILE + hh + 64] = scr[kt].z * inv;
        sP[rr * KTILE + hh + 96] = scr[kt].w * inv;
        // stage V tile
        const float4* gV = (const float4*)(Vg + base + (size_t)kt * KTILE * ND);
        #pragma unroll
        for (int i = 0; i < 8; ++i) {
            const int f = tid + NTHREADS * i;
            ((float4*)(sK + (f >> 4) * KSTR))[f & 15] = gV[f];
        }
        __syncthreads();
        // wave w covers k-subrange [w*32, w*32+32); lane = d
        const int kb0 = w * 32;
        for (int kk = 0; kk < 32; kk += 4) {
            const int kb = kb0 + kk;
            const float v0 = sK[(kb + 0) * KSTR + l];
            const float v1 = sK[(kb + 1) * KSTR + l];
            const float v2 = sK[(kb + 2) * KSTR + l];
            const float v3 = sK[(kb + 3) * KSTR + l];
            #pragma unroll
            for (int r = 0; r < QT; ++r) {
                const float4 p = ((const float4*)(sP + r * KTILE))[kb >> 2];
                po[r] = fmaf(p.x, v0, po[r]);
                po[r] = fmaf(p.y, v1, po[r]);
                po[r] = fmaf(p.z, v2, po[r]);
                po[r] = fmaf(p.w, v3, po[r]);
            }
        }
        __syncthreads();
    }

    // ---------------- cross-wave reduce + write out ----------------
    float* sRed = sK;  // 4*8*64 = 2048 floats, reuse staging buffer
    #pragma unroll
    for (int r = 0; r < QT; ++r) sRed[(w * QT + r) * ND + l] = po[r];
    __syncthreads();
    for (int i = tid; i < QT * ND; i += NTHREADS) {
        const int r = i >> 6, dd = i & 63;
        const float v = (sRed[(0 * QT + r) * ND + dd] + sRed[(1 * QT + r) * ND + dd])
                      + (sRed[(2 * QT + r) * ND + dd] + sRed[(3 * QT + r) * ND + dd]);
        outO[base + (size_t)(q0 + r) * ND + dd] = v;
    }
}

extern "C" void kernel_launch(void* const* d_in, const int* in_sizes, int n_in,
                              void* d_out, int out_size, void* d_ws, size_t ws_size,
                              hipStream_t stream) {
    const float* Qg = (const float*)d_in[0];
    const float* Kg = (const float*)d_in[1];
    const float* Vg = (const float*)d_in[2];
    const int*   Mg = (const int*)d_in[3];
    float* outO = (float*)d_out;
    float* outP = (float*)d_out + (size_t)NB * NH * NS * ND;

    dim3 grid(NBH * (NS / QT));   // 16 * 256 = 4096 blocks
    attn_fp32_kernel<<<grid, NTHREADS, 0, stream>>>(Qg, Kg, Vg, Mg, outO, outP);
}

// Round 2
// 406.247 us; speedup vs baseline: 2.0136x; 2.0136x over previous
//
#include <hip/hip_runtime.h>
#include <hip/hip_bf16.h>
#include <math.h>

#define NB 2
#define NH 8
#define NS 2048
#define ND 64
#define NBH (NB*NH)
#define QB 128            // q rows per block
#define KT 64             // k cols per staged tile
#define NTILES (NS/KT)    // 32
#define NTHR 512
#define KSTR 72           // padded bf16 row stride (144 B = 16*9 -> conflict-free b128)

typedef short bf16x8 __attribute__((ext_vector_type(8)));
typedef short bf16x4 __attribute__((ext_vector_type(4)));
typedef float f32x16 __attribute__((ext_vector_type(16)));

__device__ __forceinline__ short f2bf_trunc(float x){
  unsigned u = __builtin_bit_cast(unsigned, x);
  return (short)(u >> 16);
}
__device__ __forceinline__ float bf2f(short s){
  unsigned u = ((unsigned)(unsigned short)s) << 16;
  return __builtin_bit_cast(float, u);
}
__device__ __forceinline__ short f2bf_rn(float x){
  unsigned u = __builtin_bit_cast(unsigned, x);
  unsigned r = u + 0x7FFFu + ((u >> 16) & 1u);
  return (short)(r >> 16);
}
// exact 3-term bf16 split: x = h + m + lo + eps, |eps| <= 2^-24|x|
__device__ __forceinline__ void split3(float x, short &h, short &m, short &lo){
  h = f2bf_trunc(x);  float fh = bf2f(h);
  float r1 = x - fh;  m = f2bf_trunc(r1); float fm = bf2f(m);
  float r2 = r1 - fm; lo = f2bf_trunc(r2);
}

__global__ __launch_bounds__(NTHR, 2)
void attn_mfma_kernel(const float* __restrict__ Qg, const float* __restrict__ Kg,
                      const float* __restrict__ Vg, const int* __restrict__ Mg,
                      float* __restrict__ outO, float* __restrict__ outP)
{
  __shared__ __align__(16) short sKh[KT*KSTR];
  __shared__ __align__(16) short sKm[KT*KSTR];
  __shared__ __align__(16) short sKl[KT*KSTR];
  __shared__ __align__(16) short sVT[ND*KSTR];
  __shared__ __align__(16) short sP[QB*KSTR];      // [128 q][72] bf16
  __shared__ unsigned sMaskW[NS/32];               // 64 words of mask bits
  __shared__ float sRedM[8*32], sRedS[8*32];

  const int tid = threadIdx.x;
  const int w  = tid >> 6;       // wave 0..7
  const int l  = tid & 63;
  const int wm = w >> 1;         // M-group 0..3 (32 q rows each)
  const int wn = w & 1;          // N-half  0..1 (32 k cols each)
  const int lc = l & 31;
  const int lh = l >> 5;

  const int bh = blockIdx.x >> 4;
  const int q0 = (blockIdx.x & 15) * QB;
  const int bb = bh >> 3;
  const size_t base = (size_t)bh * NS * ND;

  // ---- mask bits -> LDS ----
  if (tid < NS/32) {
    unsigned wbits = 0;
    const int* mp = Mg + bb*NS + tid*32;
    #pragma unroll
    for (int i = 0; i < 32; ++i) wbits |= (mp[i] ? (1u << i) : 0u);
    sMaskW[tid] = wbits;
  }

  // ---- Q fragments (3-term split) held in registers ----
  bf16x8 qh[4], qm[4], ql[4];
  {
    const float* qp = Qg + base + (size_t)(q0 + wm*32 + lc) * ND;
    #pragma unroll
    for (int ks = 0; ks < 4; ++ks) {
      const int d0 = ks*16 + lh*8;
      float4 f0 = *(const float4*)(qp + d0);
      float4 f1 = *(const float4*)(qp + d0 + 4);
      float xs[8] = {f0.x,f0.y,f0.z,f0.w,f1.x,f1.y,f1.z,f1.w};
      #pragma unroll
      for (int j = 0; j < 8; ++j) {
        short h, m, lo; split3(xs[j], h, m, lo);
        qh[ks][j] = h; qm[ks][j] = m; ql[ks][j] = lo;
      }
    }
  }

  // ---- staging thread mappings ----
  const int s_kk = tid >> 3;           // 0..63 (k row)
  const int s_d8 = (tid & 7) * 8;      // 0..56 (d offset)
  float4 ka, kb;
  auto loadK = [&](int kt){
    const float* kp = Kg + base + (size_t)(kt*KT + s_kk)*ND + s_d8;
    ka = *(const float4*)(kp);
    kb = *(const float4*)(kp + 4);
  };
  auto writeK = [&](){
    float xs[8] = {ka.x,ka.y,ka.z,ka.w,kb.x,kb.y,kb.z,kb.w};
    bf16x8 vh, vm, vl;
    #pragma unroll
    for (int j = 0; j < 8; ++j) {
      short h, m, lo; split3(xs[j], h, m, lo);
      vh[j] = h; vm[j] = m; vl[j] = lo;
    }
    const int off = s_kk*KSTR + s_d8;
    *(bf16x8*)(&sKh[off]) = vh;
    *(bf16x8*)(&sKm[off]) = vm;
    *(bf16x8*)(&sKl[off]) = vl;
  };

  const int v_dd = tid & 63;           // d
  const int v_k4 = (tid >> 6) * 4;     // k base (0..28)
  float va[4], vb[4];
  auto loadV = [&](int kt){
    const float* vp = Vg + base + (size_t)(kt*KT)*ND + v_dd;
    #pragma unroll
    for (int i = 0; i < 4; ++i) {
      va[i] = vp[(v_k4 + i) * ND];
      vb[i] = vp[(v_k4 + 32 + i) * ND];
    }
  };
  auto writeV = [&](){
    const int swz = ((v_dd >> 3) & 7) << 3;
    bf16x4 pa, pb;
    #pragma unroll
    for (int i = 0; i < 4; ++i) { pa[i] = f2bf_rn(va[i]); pb[i] = f2bf_rn(vb[i]); }
    *(bf16x4*)(&sVT[v_dd*KSTR + (v_k4 ^ swz)])        = pa;
    *(bf16x4*)(&sVT[v_dd*KSTR + ((v_k4 + 32) ^ swz)]) = pb;
  };

  // ---- QK^T tile: 24 MFMAs into accA (hh) + accB (cross terms) ----
  auto qk_tile = [&](f32x16 &accA, f32x16 &accB){
    #pragma unroll
    for (int ks = 0; ks < 4; ++ks) {
      const int off = (wn*32 + lc)*KSTR + ks*16 + lh*8;
      bf16x8 b_h = *(const bf16x8*)(&sKh[off]);
      bf16x8 b_m = *(const bf16x8*)(&sKm[off]);
      bf16x8 b_l = *(const bf16x8*)(&sKl[off]);
      accA = __builtin_amdgcn_mfma_f32_32x32x16_bf16(qh[ks], b_h, accA, 0, 0, 0);
      accB = __builtin_amdgcn_mfma_f32_32x32x16_bf16(qh[ks], b_m, accB, 0, 0, 0);
      accB = __builtin_amdgcn_mfma_f32_32x32x16_bf16(qm[ks], b_h, accB, 0, 0, 0);
      accB = __builtin_amdgcn_mfma_f32_32x32x16_bf16(qm[ks], b_m, accB, 0, 0, 0);
      accB = __builtin_amdgcn_mfma_f32_32x32x16_bf16(qh[ks], b_l, accB, 0, 0, 0);
      accB = __builtin_amdgcn_mfma_f32_32x32x16_bf16(ql[ks], b_h, accB, 0, 0, 0);
    }
  };

  // =============== PASS 1: online max / sum ===============
  float mx[16], sm[16];
  #pragma unroll
  for (int r = 0; r < 16; ++r) { mx[r] = -INFINITY; sm[r] = 0.f; }

  loadK(0);
  #pragma unroll 1
  for (int kt = 0; kt < NTILES; ++kt) {
    writeK();
    __syncthreads();
    if (kt + 1 < NTILES) loadK(kt + 1);

    f32x16 accA, accB;
    #pragma unroll
    for (int r = 0; r < 16; ++r) { accA[r] = 0.f; accB[r] = 0.f; }
    qk_tile(accA, accB);

    const unsigned mbit = (sMaskW[kt*2 + wn] >> lc) & 1u;
    #pragma unroll
    for (int r = 0; r < 16; ++r) {
      float qk = accA[r] + accB[r];
      float s  = mbit ? __expf(qk) * 0.125f : -1e9f;
      float d  = s - mx[r];
      float e  = __expf(-__builtin_fabsf(d));
      bool  gt = d > 0.f;
      sm[r] = gt ? __builtin_fmaf(sm[r], e, 1.f) : (sm[r] + e);
      mx[r] = gt ? s : mx[r];
    }
    __syncthreads();
  }

  // prefetch pass-2 tile 0 while reducing
  loadK(0); loadV(0);

  // in-wave butterfly over the 32 lanes of each half
  #pragma unroll
  for (int r = 0; r < 16; ++r) {
    float m0 = mx[r], s0 = sm[r];
    #pragma unroll
    for (int st = 1; st < 32; st <<= 1) {
      float mo = __shfl_xor(m0, st, 64);
      float so = __shfl_xor(s0, st, 64);
      float nm = fmaxf(m0, mo);
      s0 = s0 * __expf(m0 - nm) + so * __expf(mo - nm);
      m0 = nm;
    }
    mx[r] = m0; sm[r] = s0;
  }
  // cross-wave (wn pair) combine via LDS
  #pragma unroll
  for (int r = 0; r < 16; ++r) {
    const int row_l = 4*lh + (r & 3) + 8*(r >> 2);
    if (lc == 0) { sRedM[w*32 + row_l] = mx[r]; sRedS[w*32 + row_l] = sm[r]; }
  }
  __syncthreads();
  float inv[16];
  #pragma unroll
  for (int r = 0; r < 16; ++r) {
    const int row_l = 4*lh + (r & 3) + 8*(r >> 2);
    float mo = sRedM[(w ^ 1)*32 + row_l];
    float so = sRedS[(w ^ 1)*32 + row_l];
    float nm = fmaxf(mx[r], mo);
    float s0 = sm[r] * __expf(mx[r] - nm) + so * __expf(mo - nm);
    mx[r] = nm; inv[r] = 1.0f / s0;
  }

  // =============== PASS 2: p write + PV ===============
  f32x16 accPV;
  #pragma unroll
  for (int r = 0; r < 16; ++r) accPV[r] = 0.f;

  #pragma unroll 1
  for (int kt = 0; kt < NTILES; ++kt) {
    writeK(); writeV();
    __syncthreads();
    if (kt + 1 < NTILES) { loadK(kt + 1); loadV(kt + 1); }

    f32x16 accA, accB;
    #pragma unroll
    for (int r = 0; r < 16; ++r) { accA[r] = 0.f; accB[r] = 0.f; }
    qk_tile(accA, accB);   // bit-identical to pass 1

    const unsigned mbit = (sMaskW[kt*2 + wn] >> lc) & 1u;
    float p[16];
    #pragma unroll
    for (int r = 0; r < 16; ++r) {
      float qk = accA[r] + accB[r];
      float s  = mbit ? __expf(qk) * 0.125f : -1e9f;
      p[r] = __expf(s - mx[r]) * inv[r];
    }

    // p -> global (paired float2, 128B segments) and -> sP (bf16, packed b32)
    #pragma unroll
    for (int r = 0; r < 16; ++r) {
      const int row_l = 4*lh + (r & 3) + 8*(r >> 2);
      float po = __shfl_xor(p[r], 1, 64);
      if (!(l & 1)) {
        float* pd = outP + ((size_t)bh*NS + q0 + wm*32 + row_l)*NS + kt*KT + wn*32 + lc;
        float2 f2; f2.x = p[r]; f2.y = po;
        *(float2*)pd = f2;
        unsigned pk = (unsigned)(unsigned short)f2bf_rn(p[r])
                    | ((unsigned)(unsigned short)f2bf_rn(po) << 16);
        *(unsigned*)(&sP[(wm*32 + row_l)*KSTR + wn*32 + lc]) = pk;
      }
    }
    __syncthreads();

    // PV: C[32q][32d] += P[32q][64k] * V[64k][32d]
    #pragma unroll
    for (int ks = 0; ks < 4; ++ks) {
      bf16x8 pa = *(const bf16x8*)(&sP[(wm*32 + lc)*KSTR + ks*16 + lh*8]);
      const int dg  = wn*32 + lc;
      const int swz = ((dg >> 3) & 7) << 3;
      bf16x8 vB = *(const bf16x8*)(&sVT[dg*KSTR + ((ks*16 + lh*8) ^ swz)]);
      accPV = __builtin_amdgcn_mfma_f32_32x32x16_bf16(pa, vB, accPV, 0, 0, 0);
    }
    __syncthreads();
  }

  // ---- O write ----
  #pragma unroll
  for (int r = 0; r < 16; ++r) {
    const int row_l = 4*lh + (r & 3) + 8*(r >> 2);
    outO[base + (size_t)(q0 + wm*32 + row_l)*ND + wn*32 + lc] = accPV[r];
  }
}

extern "C" void kernel_launch(void* const* d_in, const int* in_sizes, int n_in,
                              void* d_out, int out_size, void* d_ws, size_t ws_size,
                              hipStream_t stream) {
  const float* Qg = (const float*)d_in[0];
  const float* Kg = (const float*)d_in[1];
  const float* Vg = (const float*)d_in[2];
  const int*   Mg = (const int*)d_in[3];
  float* outO = (float*)d_out;
  float* outP = (float*)d_out + (size_t)NB*NH*NS*ND;

  dim3 grid(NBH * (NS / QB));   // 16 * 16 = 256 blocks
  attn_mfma_kernel<<<grid, NTHR, 0, stream>>>(Qg, Kg, Vg, Mg, outO, outP);
}